// Round 1
// baseline (177.081 us; speedup 1.0000x reference)
//
#include <hip/hip_runtime.h>
#include <math.h>

// Problem constants (scale_idx is fixed to 0 in setup_inputs: H=W=80, anchors 0..2)
namespace {
constexpr int kNImg = 64;
constexpr int kM    = 40;   // boxes per image
constexpr int kA    = 3;    // anchors at this scale
constexpr int kNC   = 20;
constexpr int kH    = 80;
constexpr int kW    = 80;
constexpr int kHW   = kH * kW;        // 6400
constexpr int kHW4  = kHW / 4;        // 1600 float4 per channel plane
constexpr int kC    = 5 + kNC;        // 25
constexpr int kPlanes = kNImg * kA;   // 192 (n,a) planes
constexpr int kVPP  = (1 + kNC) * kHW4;   // 33600 float4 of obj+cls per plane
constexpr int kNV   = kPlanes * kVPP;     // 6451200 float4 total (dense pass)
constexpr double kObjCnt = 1228800.0;     // 64*3*6400
constexpr double kClsCnt = 24576000.0;    // 64*3*20*6400
constexpr int kGrid = 1024;
}

__device__ __forceinline__ float wave_red(float v) {
#pragma unroll
  for (int o = 32; o > 0; o >>= 1) v += __shfl_down(v, o, 64);
  return v;
}
__device__ __forceinline__ double wave_red_d(double v) {
#pragma unroll
  for (int o = 32; o > 0; o >>= 1) v += __shfl_down(v, o, 64);
  return v;
}

// softplus(x) = max(x,0) + log1p(exp(-|x|)); fast intrinsics are fine
// (abs err ~1e-7 per element vs 2.5e-2 threshold on the final scalar).
__device__ __forceinline__ float softplus_fast(float x) {
  return fmaxf(x, 0.0f) + __logf(1.0f + __expf(-fabsf(x)));
}

__global__ __launch_bounds__(256) void yolo_main(
    const float* __restrict__ preds, const float* __restrict__ boxes,
    const int* __restrict__ labels, double* __restrict__ part, int nblocks) {
  __shared__ int s_keys[64];
  __shared__ float s_red[4][5];
  const int tid = threadIdx.x;
  const int bid = blockIdx.x;

  // Per-thread contributions (only wave 0 of blocks < 64 produces box terms)
  float corr_obj = 0.0f, corr_cls = 0.0f, iou_acc = 0.0f;
  int mykey = -1, best = 0, gx = 0, gy = 0, lab = 0;
  float dx = 0.0f, dy = 0.0f, twv = 0.0f, thv = 0.0f;

  const float ancw[3] = {10.0f / 640.0f, 16.0f / 640.0f, 33.0f / 640.0f};
  const float anch[3] = {13.0f / 640.0f, 30.0f / 640.0f, 23.0f / 640.0f};

  // ---- Phase P: per-image box prep + dedup key (image = bid for bid<64) ----
  if (bid < kNImg && tid < 64) {
    int key = -1;
    if (tid < kM) {
      const float* bp = boxes + ((bid * kM + tid) << 2);
      float x1 = bp[0], y1 = bp[1], x2 = bp[2], y2 = bp[3];
      bool valid = (x2 > x1) && (y2 > y1);
      float cx = ((x1 + x2) * 0.5f) / 640.0f;
      float cy = ((y1 + y2) * 0.5f) / 640.0f;
      float w = (x2 - x1) / 640.0f;
      float h = (y2 - y1) / 640.0f;
      float fx = cx * (float)kW;
      float fy = cy * (float)kH;
      gx = (int)floorf(fx);
      gy = (int)floorf(fy);
      dx = fx - (float)gx;
      dy = fy - (float)gy;
      float bestv = -1e30f;
      int b = 0;
#pragma unroll
      for (int a = 0; a < 3; ++a) {
        float rw = w / ancw[a];
        float rh = h / anch[a];
        float i1 = fminf(rw, 1.0f / rw) * fminf(rh, 1.0f / rh);
        if (i1 > bestv) { bestv = i1; b = a; }  // strict > == argmax-first (matches jnp)
      }
      best = b;
      twv = logf(w / ancw[b] + 1e-6f);
      thv = logf(h / anch[b] + 1e-6f);
      lab = labels[bid * kM + tid];
      if (valid && gx >= 0 && gx < kW && gy >= 0 && gy < kH)
        key = (b * kH + gy) * kW + gx;  // cell identity: (anchor, gy, gx)
    }
    s_keys[tid] = key;
    mykey = key;
  }
  __syncthreads();

  // Winner = last (max m) valid box per cell -> matches in-order scatter .set()
  if (mykey >= 0) {
    bool win = true;
    for (int mp = tid + 1; mp < kM; ++mp)
      if (s_keys[mp] == mykey) { win = false; break; }
    if (win) {
      const float* pp =
          preds + (size_t)(bid * kA + best) * kC * kHW + (gy * kW + gx);
      float xtx = pp[0];
      float xty = pp[kHW];
      float xtw = pp[2 * kHW];
      float xth = pp[3 * kHW];
      float xob = pp[4 * kHW];
      float xcl = pp[(5 + lab) * kHW];
      // bce(x,1) - bce(x,0) = -x  (obj target=1 and one-hot cls target)
      corr_obj = -xob;
      corr_cls = -xcl;
      float aw = ancw[best], ah = anch[best];
      float sx = 1.0f / (1.0f + expf(-xtx));
      float sy = 1.0f / (1.0f + expf(-xty));
      float sw = 1.0f / (1.0f + expf(-xtw));
      float sh = 1.0f / (1.0f + expf(-xth));
      float px = (2.0f * sx - 0.5f + (float)gx) * 8.0f;
      float py = (2.0f * sy - 0.5f + (float)gy) * 8.0f;
      float pw = (2.0f * sw) * (2.0f * sw) * aw;
      float ph = (2.0f * sh) * (2.0f * sh) * ah;
      float tx = (dx + (float)gx) * 8.0f;
      float ty = (dy + (float)gy) * 8.0f;
      float tw2 = expf(twv) * aw;
      float th2 = expf(thv) * ah;
      float b1x1 = px - pw * 0.5f, b1x2 = px + pw * 0.5f;
      float b1y1 = py - ph * 0.5f, b1y2 = py + ph * 0.5f;
      float b2x1 = tx - tw2 * 0.5f, b2x2 = tx + tw2 * 0.5f;
      float b2y1 = ty - th2 * 0.5f, b2y2 = ty + th2 * 0.5f;
      float iw = fmaxf(fminf(b1x2, b2x2) - fmaxf(b1x1, b2x1), 0.0f);
      float ih = fmaxf(fminf(b1y2, b2y2) - fmaxf(b1y1, b2y1), 0.0f);
      float inter = iw * ih;
      float uni = (b1x2 - b1x1) * (b1y2 - b1y1) +
                  (b2x2 - b2x1) * (b2y2 - b2y1) - inter + 1e-7f;
      iou_acc = inter / uni;
    }
  }

  // ---- Phase D: dense softplus over obj (ch4) + cls (ch5..24) planes ----
  // Channels 0..3 are never read here: 103 MB instead of 123 MB.
  float sp_obj = 0.0f, sp_cls = 0.0f;
  const float4* pv = (const float4*)preds;
  const int stride = nblocks * 256;
  for (int i = bid * 256 + tid; i < kNV; i += stride) {
    int plane = i / kVPP;
    int rem = i - plane * kVPP;
    float4 v = pv[plane * (kC * kHW4) + 4 * kHW4 + rem];
    float s = softplus_fast(v.x) + softplus_fast(v.y) + softplus_fast(v.z) +
              softplus_fast(v.w);
    if (rem < kHW4) sp_obj += s;  // channel 4 (obj)
    else sp_cls += s;             // channels 5..24 (cls)
  }

  // ---- Block reduction of 5 partials -> part[bid][0..4] ----
  float vals[5] = {sp_obj, sp_cls, corr_obj, corr_cls, iou_acc};
#pragma unroll
  for (int j = 0; j < 5; ++j) vals[j] = wave_red(vals[j]);
  const int wid = tid >> 6, lane = tid & 63;
  if (lane == 0) {
#pragma unroll
    for (int j = 0; j < 5; ++j) s_red[wid][j] = vals[j];
  }
  __syncthreads();
  if (tid == 0) {
#pragma unroll
    for (int j = 0; j < 5; ++j) {
      double s = (double)s_red[0][j] + (double)s_red[1][j] +
                 (double)s_red[2][j] + (double)s_red[3][j];
      part[bid * 5 + j] = s;
    }
  }
}

__global__ __launch_bounds__(256) void yolo_finalize(
    const double* __restrict__ part, int nblocks, float* __restrict__ out) {
  double v[5] = {0.0, 0.0, 0.0, 0.0, 0.0};
  for (int i = threadIdx.x; i < nblocks; i += 256) {
#pragma unroll
    for (int j = 0; j < 5; ++j) v[j] += part[i * 5 + j];
  }
#pragma unroll
  for (int j = 0; j < 5; ++j) v[j] = wave_red_d(v[j]);
  __shared__ double s_red[4][5];
  const int wid = threadIdx.x >> 6, lane = threadIdx.x & 63;
  if (lane == 0) {
#pragma unroll
    for (int j = 0; j < 5; ++j) s_red[wid][j] = v[j];
  }
  __syncthreads();
  if (threadIdx.x == 0) {
    double t[5];
#pragma unroll
    for (int j = 0; j < 5; ++j)
      t[j] = s_red[0][j] + s_red[1][j] + s_red[2][j] + s_red[3][j];
    double loss_obj = (t[0] + t[2]) / kObjCnt;          // mean bce over obj
    double loss_cls = (t[1] + t[3]) / kClsCnt;          // mean bce over cls
    double loss_box = 1.0 - t[4];                       // 1 - sum(iou*pos)
    double loss = 0.05 * loss_box + 1.0 * loss_obj + 0.5 * loss_cls;
    out[0] = (float)loss;
  }
}

extern "C" void kernel_launch(void* const* d_in, const int* in_sizes, int n_in,
                              void* d_out, int out_size, void* d_ws,
                              size_t ws_size, hipStream_t stream) {
  const float* preds = (const float*)d_in[0];
  const float* boxes = (const float*)d_in[1];
  const int* labels = (const int*)d_in[2];
  float* out = (float*)d_out;

  int G = kGrid;
  size_t need = (size_t)G * 5 * sizeof(double);
  if (need > ws_size) {
    G = (int)(ws_size / (5 * sizeof(double)));
    if (G < kNImg) G = kNImg;  // must cover the 64 images in phase P
  }
  double* part = (double*)d_ws;
  // part[] is fully written by every block before finalize reads it,
  // so no memset of the poisoned workspace is needed.
  yolo_main<<<G, 256, 0, stream>>>(preds, boxes, labels, part, G);
  yolo_finalize<<<1, 256, 0, stream>>>(part, G, out);
}